// Round 3
// baseline (343.091 us; speedup 1.0000x reference)
//
#include <hip/hip_runtime.h>

// support[1::2, 1::2] of an 8192x8192 fp32 matrix -> 4096x4096 fp32.
// Memory-bound streaming gather: ~128 MiB fetch (odd rows only, full lines
// forced by odd-column interleave) + 64 MiB write -> ~30 us floor @ 6.5 TB/s.

#define IN_N 8192
#define OUT_N 4096

// Native clang vector type: __builtin_nontemporal_* requires scalar/native-
// vector pointee (HIP_vector_type float4 is a struct and is rejected).
typedef float v4f __attribute__((ext_vector_type(4)));

__global__ __launch_bounds__(256) void coarse_slice_kernel(
    const float* __restrict__ in, float* __restrict__ out) {
    // Each thread produces 8 consecutive output floats (2x 16B stores),
    // reading 16 consecutive input floats (4x 16B loads) from one odd row.
    const size_t t = (size_t)blockIdx.x * blockDim.x + threadIdx.x;
    const size_t o = t << 3;                  // flat output index (multiple of 8)
    const int r = (int)(o >> 12);             // output row   (o / 4096)
    const int c = (int)(o & (OUT_N - 1));     // output col   (multiple of 8)

    // Input row 2r+1, input cols 2c .. 2c+15 (we want odd cols 2c+1..2c+15).
    const v4f* src =
        (const v4f*)(in + (size_t)(2 * r + 1) * IN_N + (size_t)(2 * c));
    const v4f a = __builtin_nontemporal_load(src + 0); // cols 2c   .. 2c+3
    const v4f b = __builtin_nontemporal_load(src + 1); // cols 2c+4 .. 2c+7
    const v4f x = __builtin_nontemporal_load(src + 2); // cols 2c+8 .. 2c+11
    const v4f y = __builtin_nontemporal_load(src + 3); // cols 2c+12.. 2c+15

    v4f* dst = (v4f*)out + (t << 1);
    const v4f o0 = {a.y, a.w, b.y, b.w};
    const v4f o1 = {x.y, x.w, y.y, y.w};
    __builtin_nontemporal_store(o0, dst + 0);
    __builtin_nontemporal_store(o1, dst + 1);
}

extern "C" void kernel_launch(void* const* d_in, const int* in_sizes, int n_in,
                              void* d_out, int out_size, void* d_ws, size_t ws_size,
                              hipStream_t stream) {
    const float* in = (const float*)d_in[0];
    float* out = (float*)d_out;

    // 4096*4096 outputs / 8 per thread = 2,097,152 threads = 8192 blocks of 256.
    const int threads = 256;
    const int blocks = (OUT_N * OUT_N / 8) / threads;
    coarse_slice_kernel<<<blocks, threads, 0, stream>>>(in, out);
}